// Round 1
// baseline (2664.776 us; speedup 1.0000x reference)
//
#include <hip/hip_runtime.h>
#include <math.h>

#define T_ 8
#define N_ 50000
#define F0_ 128
#define H0_ 128
#define H1_ 64
#define NNZ_ 800000
#define E_ 1000000
#define K_ 128
#define CAP_ 3072

// ---------- helpers ----------
__device__ inline unsigned ford(float f) {
    unsigned b = __float_as_uint(f);
    return (b & 0x80000000u) ? ~b : (b | 0x80000000u);
}
__device__ inline float funord(unsigned u) {
    unsigned b = (u & 0x80000000u) ? (u & 0x7fffffffu) : ~u;
    return __uint_as_float(b);
}

// ---------- p_hat = p / ||p|| ----------
__global__ void k_phat(const float* p, float* p_hat) {
    __shared__ float s[128];
    int i = threadIdx.x;
    float v = p[i];
    s[i] = v * v;
    __syncthreads();
    for (int off = 64; off > 0; off >>= 1) {
        if (i < off) s[i] += s[i + off];
        __syncthreads();
    }
    p_hat[i] = v / sqrtf(s[0]);
}

// ---------- y[t][n] = dot(X[t][n], p_hat), wave per row ----------
__global__ void k_y(const float* __restrict__ X, const float* __restrict__ p_hat,
                    float* __restrict__ y) {
    int gid = blockIdx.x * 256 + threadIdx.x;
    int wave = gid >> 6, lane = gid & 63;
    if (wave >= T_ * N_) return;
    const float2* xr = (const float2*)(X + (size_t)wave * F0_);
    float2 a = xr[lane];
    float2 ph = ((const float2*)p_hat)[lane];
    float acc = a.x * ph.x + a.y * ph.y;
#pragma unroll
    for (int off = 32; off > 0; off >>= 1) acc += __shfl_down(acc, off);
    if (lane == 0) y[wave] = acc;
}

// ---------- exact top-128 per t: 2-level radix select + exact rank ----------
__global__ __launch_bounds__(1024) void k_topk(const float* __restrict__ y,
                                               float* __restrict__ topv,
                                               int* __restrict__ topidx) {
    int t = blockIdx.x;
    const float* yt = y + (size_t)t * N_;
    __shared__ int hist[256];
    __shared__ int sb1, sAbove, sP, scand;
    __shared__ unsigned cu[CAP_];
    __shared__ int cidx[CAP_];
    int tid = threadIdx.x;

    if (tid < 256) hist[tid] = 0;
    __syncthreads();
    for (int i = tid; i < N_; i += 1024) {
        unsigned u = ford(yt[i]);
        atomicAdd(&hist[u >> 24], 1);
    }
    __syncthreads();
    if (tid == 0) {
        int acc = 0, b = 255;
        for (; b >= 0; b--) { acc += hist[b]; if (acc >= K_) break; }
        sb1 = b;
        sAbove = acc - hist[b];
    }
    __syncthreads();
    int b1 = sb1;
    if (tid < 256) hist[tid] = 0;
    __syncthreads();
    for (int i = tid; i < N_; i += 1024) {
        unsigned u = ford(yt[i]);
        if ((int)(u >> 24) == b1) atomicAdd(&hist[(u >> 16) & 255], 1);
    }
    __syncthreads();
    if (tid == 0) {
        int acc = sAbove, b = 255;
        for (; b >= 0; b--) { acc += hist[b]; if (acc >= K_) break; }
        sP = (b1 << 8) | b;
        scand = 0;
    }
    __syncthreads();
    unsigned P = (unsigned)sP;
    for (int i = tid; i < N_; i += 1024) {
        unsigned u = ford(yt[i]);
        if ((u >> 16) >= P) {
            int pos = atomicAdd(&scand, 1);
            if (pos < CAP_) { cu[pos] = u; cidx[pos] = i; }
        }
    }
    __syncthreads();
    int C = min(scand, CAP_);
    for (int c = tid; c < C; c += 1024) {
        unsigned uc = cu[c];
        int ic = cidx[c];
        int rank = 0;
        for (int o = 0; o < C; o++) {
            unsigned uo = cu[o];
            rank += (uo > uc) || (uo == uc && cidx[o] < ic);
        }
        if (rank < K_) {
            topv[t * K_ + rank] = funord(uc);
            topidx[t * K_ + rank] = ic;
        }
    }
}

// ---------- Z[t][f][j] = X[t][idx[j]][f] * topv[j] ----------
__global__ void k_z(const float* __restrict__ X, const float* __restrict__ topv,
                    const int* __restrict__ topidx, float* __restrict__ Z) {
    int gid = blockIdx.x * 256 + threadIdx.x;  // t*16384 + f*128 + j
    if (gid >= T_ * F0_ * K_) return;
    int j = gid & 127;
    int f = (gid >> 7) & 127;
    int t = gid >> 14;
    int idx = topidx[t * K_ + j];
    float v = topv[t * K_ + j];
    Z[gid] = X[((size_t)(t * N_ + idx)) * F0_ + f] * v;
}

// ---------- A_g[t] = W_g @ Z_t + B_g  (g in {Z,R,H}, all t parallel) ----------
__global__ void k_az(const float* __restrict__ WZ, const float* __restrict__ WR,
                     const float* __restrict__ WH, const float* __restrict__ BZ,
                     const float* __restrict__ BR, const float* __restrict__ BH,
                     const float* __restrict__ Z, float* __restrict__ AZ,
                     float* __restrict__ AR, float* __restrict__ AHo) {
    int gid = blockIdx.x * 256 + threadIdx.x;  // g*131072 + t*16384 + i*128 + j
    int j = gid & 127;
    int i = (gid >> 7) & 127;
    int t = (gid >> 14) & 7;
    int g = gid >> 17;
    const float* W = (g == 0) ? WZ : (g == 1) ? WR : WH;
    const float* B = (g == 0) ? BZ : (g == 1) ? BR : BH;
    float* Ao = (g == 0) ? AZ : (g == 1) ? AR : AHo;
    const float* Zt = Z + (size_t)t * 16384;
    float acc = B[i * 128 + j];
    for (int k = 0; k < 128; k++) acc += W[i * 128 + k] * Zt[k * 128 + j];
    Ao[(size_t)(t * 128 + i) * 128 + j] = acc;
}

// ---------- CSR build ----------
__global__ void k_hist(const int* __restrict__ A_rows, int* __restrict__ cnt) {
    int gid = blockIdx.x * 256 + threadIdx.x;
    if (gid >= T_ * NNZ_) return;
    int t = gid / NNZ_;
    atomicAdd(&cnt[t * N_ + A_rows[gid]], 1);
}

__global__ __launch_bounds__(1024) void k_scan(const int* __restrict__ cnt,
                                               int* __restrict__ row_ptr) {
    int t = blockIdx.x;
    __shared__ int buf[1024];
    __shared__ int base_s;
    int tid = threadIdx.x;
    if (tid == 0) base_s = 0;
    __syncthreads();
    const int* c = cnt + (size_t)t * N_;
    int* rp = row_ptr + (size_t)t * (N_ + 1);
    for (int start = 0; start < N_; start += 1024) {
        int i = start + tid;
        int v = (i < N_) ? c[i] : 0;
        buf[tid] = v;
        __syncthreads();
        for (int off = 1; off < 1024; off <<= 1) {
            int x = (tid >= off) ? buf[tid - off] : 0;
            __syncthreads();
            buf[tid] += x;
            __syncthreads();
        }
        int incl = buf[tid];
        int total = buf[1023];
        int b = base_s;
        if (i < N_) rp[i] = b + incl - v;
        __syncthreads();
        if (tid == 0) base_s = b + total;
        __syncthreads();
    }
    if (tid == 0) rp[N_] = base_s;
}

__global__ void k_scatter(const int* __restrict__ A_rows, const int* __restrict__ A_cols,
                          const float* __restrict__ A_val, const int* __restrict__ row_ptr,
                          int* __restrict__ fill, int* __restrict__ e_col,
                          float* __restrict__ e_val) {
    int gid = blockIdx.x * 256 + threadIdx.x;
    if (gid >= T_ * NNZ_) return;
    int t = gid / NNZ_;
    int r = A_rows[gid];
    int pos = row_ptr[(size_t)t * (N_ + 1) + r] + atomicAdd(&fill[t * N_ + r], 1);
    e_col[(size_t)t * NNZ_ + pos] = A_cols[gid];
    e_val[(size_t)t * NNZ_ + pos] = A_val[gid];
}

// ---------- SpMM: AH[t][r] = sum_e val*X[t][col], wave per row ----------
__global__ void k_spmm(const float* __restrict__ X, const int* __restrict__ row_ptr,
                       const int* __restrict__ e_col, const float* __restrict__ e_val,
                       float* __restrict__ AH) {
    int gid = blockIdx.x * 256 + threadIdx.x;
    int wave = gid >> 6, lane = gid & 63;
    if (wave >= T_ * N_) return;
    int t = wave / N_;
    int r = wave - t * N_;
    int s = row_ptr[(size_t)t * (N_ + 1) + r];
    int e = row_ptr[(size_t)t * (N_ + 1) + r + 1];
    const float2* Xt = (const float2*)(X + (size_t)t * N_ * F0_);
    const int* ec = e_col + (size_t)t * NNZ_;
    const float* ev = e_val + (size_t)t * NNZ_;
    float2 acc = {0.f, 0.f};
    for (int q = s; q < e; q++) {
        int c = ec[q];
        float v = ev[q];
        float2 x = Xt[(size_t)c * 64 + lane];
        acc.x += v * x.x;
        acc.y += v * x.y;
    }
    ((float2*)AH)[(size_t)wave * 64 + lane] = acc;
}

// ---------- GRU sequential parts ----------
__global__ void k_gru_a(const float* __restrict__ AZt, const float* __restrict__ ARt,
                        const float* __restrict__ UZ, const float* __restrict__ UR,
                        const float* __restrict__ Wprev, float* __restrict__ Zg,
                        float* __restrict__ Rg) {
    int gid = blockIdx.x * 256 + threadIdx.x;  // i*128 + j
    int j = gid & 127, i = gid >> 7;
    float az = AZt[gid], ar = ARt[gid];
    for (int k = 0; k < 128; k++) {
        float w = Wprev[k * 128 + j];
        az += UZ[i * 128 + k] * w;
        ar += UR[i * 128 + k] * w;
    }
    Zg[gid] = 1.f / (1.f + expf(-az));
    Rg[gid] = 1.f / (1.f + expf(-ar));
}

__global__ void k_gru_b(const float* __restrict__ AHt, const float* __restrict__ UH,
                        const float* __restrict__ Wprev, const float* __restrict__ Zg,
                        const float* __restrict__ Rg, float* __restrict__ Wnew) {
    int gid = blockIdx.x * 256 + threadIdx.x;
    int j = gid & 127, i = gid >> 7;
    float acc = AHt[gid];
    for (int k = 0; k < 128; k++)
        acc += UH[i * 128 + k] * (Rg[k * 128 + j] * Wprev[k * 128 + j]);
    float ht = tanhf(acc);
    float w = Wprev[gid], z = Zg[gid];
    Wnew[gid] = (1.f - z) * w + z * ht;
}

// ---------- WU[t][k][h2] = sum_m W_t[k][m] * U[(h2<64? m : 128+m)][h2&63] ----------
__global__ void k_wu(const float* __restrict__ W_seq, const float* __restrict__ U,
                     float* __restrict__ WU) {
    int blk = blockIdx.x;  // t*128 + k
    int t = blk >> 7, k = blk & 127;
    int h2 = threadIdx.x;
    const float* Wt = W_seq + (size_t)t * 16384;
    int h = h2 & 63;
    const float* Ub = U + (h2 < 64 ? 0 : 128 * 64);
    float acc = 0.f;
    for (int m = 0; m < 128; m++) acc += Wt[k * 128 + m] * Ub[m * 64 + h];
    WU[((size_t)t * 128 + k) * 128 + h2] = acc;
}

// ---------- PQ = AH @ WU[t]  (in place on AH) ----------
__global__ void k_pq(float* __restrict__ AH, const float* __restrict__ WU) {
    __shared__ float rows[2][128];
    int r0 = blockIdx.x * 2;
    int tid = threadIdx.x;
    rows[tid >> 7][tid & 127] = AH[(size_t)r0 * 128 + tid];
    __syncthreads();
    int rl = tid >> 7, h2 = tid & 127;
    int r = r0 + rl;
    int t = r / N_;
    const float* wu = WU + (size_t)t * 16384;
    float acc = 0.f;
#pragma unroll 4
    for (int k = 0; k < 128; k++) acc += rows[rl][k] * wu[k * 128 + h2];
    AH[(size_t)r * 128 + h2] = acc;
}

// ---------- out[e] = P[flat_src] + Q[flat_trg] ----------
__global__ void k_final(const float* __restrict__ PQ, const int* __restrict__ et,
                        const int* __restrict__ es, const int* __restrict__ eg,
                        float* __restrict__ out) {
    int gid = blockIdx.x * 256 + threadIdx.x;  // e*16 + q
    if (gid >= E_ * 16) return;
    int e = gid >> 4, q = gid & 15;
    int t = et[e];
    const float4 a = *(const float4*)(PQ + ((size_t)(t * N_ + es[e])) * 128 + q * 4);
    const float4 b = *(const float4*)(PQ + ((size_t)(t * N_ + eg[e])) * 128 + 64 + q * 4);
    float4 o = {a.x + b.x, a.y + b.y, a.z + b.z, a.w + b.w};
    *(float4*)(out + (size_t)e * 64 + q * 4) = o;
}

__global__ void k_wfin(const float* __restrict__ W_seq, float* __restrict__ out) {
    int gid = blockIdx.x * 256 + threadIdx.x;
    out[(size_t)E_ * 64 + gid] = W_seq[(size_t)7 * 16384 + gid];
}

// ---------- launch ----------
extern "C" void kernel_launch(void* const* d_in, const int* in_sizes, int n_in,
                              void* d_out, int out_size, void* d_ws, size_t ws_size,
                              hipStream_t stream) {
    const float* X = (const float*)d_in[0];
    const int* A_rows = (const int*)d_in[1];
    const int* A_cols = (const int*)d_in[2];
    const float* A_val = (const float*)d_in[3];
    const int* edge_time = (const int*)d_in[4];
    const int* edge_src = (const int*)d_in[5];
    const int* edge_trg = (const int*)d_in[6];
    const float* p = (const float*)d_in[7];
    const float* W_Z = (const float*)d_in[8];
    const float* U_Z = (const float*)d_in[9];
    const float* B_Z = (const float*)d_in[10];
    const float* W_R = (const float*)d_in[11];
    const float* U_R = (const float*)d_in[12];
    const float* B_R = (const float*)d_in[13];
    const float* W_H = (const float*)d_in[14];
    const float* U_H = (const float*)d_in[15];
    const float* B_H = (const float*)d_in[16];
    const float* W_init = (const float*)d_in[17];
    const float* U = (const float*)d_in[18];
    float* out = (float*)d_out;

    char* ws = (char*)d_ws;
    size_t off = 0;
    auto take = [&](size_t bytes) {
        char* ptr = ws + off;
        off = (off + bytes + 255) & ~(size_t)255;
        return (void*)ptr;
    };
    float* AH = (float*)take((size_t)T_ * N_ * F0_ * 4);      // 204.8 MB, becomes PQ in place
    int* e_col = (int*)take((size_t)T_ * NNZ_ * 4);           // 25.6 MB
    float* e_val = (float*)take((size_t)T_ * NNZ_ * 4);       // 25.6 MB
    float* yv = (float*)take((size_t)T_ * N_ * 4);
    int* row_ptr = (int*)take((size_t)T_ * (N_ + 1) * 4);
    int* cnt = (int*)take((size_t)T_ * N_ * 4);
    int* fill = (int*)take((size_t)T_ * N_ * 4);
    float* p_hat = (float*)take(512);
    float* topv = (float*)take((size_t)T_ * K_ * 4);
    int* topidx = (int*)take((size_t)T_ * K_ * 4);
    float* Z = (float*)take((size_t)T_ * F0_ * K_ * 4);
    float* AZb = (float*)take((size_t)T_ * 16384 * 4);
    float* ARb = (float*)take((size_t)T_ * 16384 * 4);
    float* AHb = (float*)take((size_t)T_ * 16384 * 4);
    float* Zg = (float*)take(16384 * 4);
    float* Rg = (float*)take(16384 * 4);
    float* W_seq = (float*)take((size_t)T_ * 16384 * 4);
    float* WU = (float*)take((size_t)T_ * 16384 * 4);

    hipMemsetAsync(cnt, 0, (size_t)T_ * N_ * 4, stream);
    hipMemsetAsync(fill, 0, (size_t)T_ * N_ * 4, stream);

    k_phat<<<1, 128, 0, stream>>>(p, p_hat);
    k_y<<<(T_ * N_ * 64) / 256, 256, 0, stream>>>(X, p_hat, yv);
    k_topk<<<T_, 1024, 0, stream>>>(yv, topv, topidx);
    k_z<<<(T_ * F0_ * K_) / 256, 256, 0, stream>>>(X, topv, topidx, Z);
    k_az<<<(3 * T_ * 16384) / 256, 256, 0, stream>>>(W_Z, W_R, W_H, B_Z, B_R, B_H, Z,
                                                     AZb, ARb, AHb);
    k_hist<<<(T_ * NNZ_ + 255) / 256, 256, 0, stream>>>(A_rows, cnt);
    k_scan<<<T_, 1024, 0, stream>>>(cnt, row_ptr);
    k_scatter<<<(T_ * NNZ_ + 255) / 256, 256, 0, stream>>>(A_rows, A_cols, A_val, row_ptr,
                                                           fill, e_col, e_val);
    k_spmm<<<(T_ * N_ * 64) / 256, 256, 0, stream>>>(X, row_ptr, e_col, e_val, AH);
    for (int t = 0; t < T_; t++) {
        const float* Wprev = (t == 0) ? W_init : (W_seq + (size_t)(t - 1) * 16384);
        k_gru_a<<<64, 256, 0, stream>>>(AZb + (size_t)t * 16384, ARb + (size_t)t * 16384,
                                        U_Z, U_R, Wprev, Zg, Rg);
        k_gru_b<<<64, 256, 0, stream>>>(AHb + (size_t)t * 16384, U_H, Wprev, Zg, Rg,
                                        W_seq + (size_t)t * 16384);
    }
    k_wu<<<T_ * 128, 128, 0, stream>>>(W_seq, U, WU);
    k_pq<<<T_ * N_ / 2, 256, 0, stream>>>(AH, WU);
    k_final<<<(E_ * 16) / 256, 256, 0, stream>>>(AH, edge_time, edge_src, edge_trg, out);
    k_wfin<<<(F0_ * H0_) / 256, 256, 0, stream>>>(W_seq, out);
}